// Round 7
// baseline (59.181 us; speedup 1.0000x reference)
//
#include <hip/hip_runtime.h>
#include <hip/hip_bf16.h>

#define NN 50000
#define NE 320000
#define HID 256
#define NBLK_FLAG 1250            // ceil(NE/256)
#define FLAG_MAGIC 0x7F3A9C51
#define GRID_GEMM 521             // 521 * 3 == 1563 tiles exactly
#define NTILES 1563

typedef __attribute__((ext_vector_type(8))) short bf16x8;   // 8 bf16 = 4 VGPR
typedef __attribute__((ext_vector_type(4))) float f32x4;

static __device__ __forceinline__ short f2bf(float f) {
    union { __hip_bfloat16 h; short s; } u;
    u.h = __float2bfloat16(f);     // RNE; pairs pack to v_cvt_pk_bf16_f32
    return u.s;
}

// ---------------- prep: flags scatter + W2=Wv@Wo (bf16 fragment image) ----------------
// wsB layout = per-wave MFMA B fragments, coalesced:
//   byte off = kt*32768 + c16*2048 + kk*1024 + h*256 + rl*16 + e*2
// where k = kt*64 + kk*32 + h*8 + e, col = c16*16 + rl.
// Flags: idempotent FLAG_MAGIC scatter (inputs fixed); 0xAA poison never matches.
__global__ void prep_k(const int* __restrict__ ei, int* __restrict__ flags,
                       const float* __restrict__ Wv, const float* __restrict__ Wo,
                       unsigned short* __restrict__ wsB) {
    const int b = blockIdx.x;
    if (b < NBLK_FLAG) {
        __shared__ int nz;
        if (threadIdx.x == 0) nz = 0;
        __syncthreads();
        unsigned hv = ((const unsigned*)ei)[2 * threadIdx.x + 1];
        if (hv != 0u) nz = 1;              // benign same-value race
        __syncthreads();
        const int is64 = (nz == 0);        // int64 => high dwords all zero
        const int e = b * 256 + threadIdx.x;
        if (e < NE) {
            int t = is64 ? ei[2 * (NE + e)] : ei[NE + e];
            if (t >= 0 && t < NN) flags[t] = FLAG_MAGIC;   // benign same-value race
        }
    } else {
        const int i = b - NBLK_FLAG;       // W2 row == GEMM k, 0..255 (one row per block)
        const int j = threadIdx.x;         // col
        const float* wv = Wv + i * HID;    // wave-uniform scalar loads
        float s0 = 0.f, s1 = 0.f, s2 = 0.f, s3 = 0.f;
        #pragma unroll 8
        for (int k = 0; k < HID; k += 4) {
            s0 = fmaf(wv[k + 0], Wo[(k + 0) * HID + j], s0);
            s1 = fmaf(wv[k + 1], Wo[(k + 1) * HID + j], s1);
            s2 = fmaf(wv[k + 2], Wo[(k + 2) * HID + j], s2);
            s3 = fmaf(wv[k + 3], Wo[(k + 3) * HID + j], s3);
        }
        const float acc = (s0 + s1) + (s2 + s3);
        const int kt = i >> 6, kp = i & 63;
        const int kk = kp >> 5, h = (kp >> 3) & 3, e = kp & 7;
        wsB[(kt * 32768 + (j >> 4) * 2048 + kk * 1024 + h * 256 + (j & 15) * 16 + e * 2) >> 1]
            = (unsigned short)f2bf(acc);
    }
}

// ---------------- out = mask ? x @ W2 + bo : bo  (bf16 MFMA, persistent+pipelined) ----------------
// 521 persistent blocks x 3 tiles (32 rows x 256 cols each). Per tile: stage A->LDS,
// load B kt0/kt1 (L2), issue NEXT tile's x-loads (HBM, counted-vmcnt keeps them in
// flight), raw s_barrier with lgkmcnt(0) only (no vmcnt drain), MFMA with mid-loop
// B kt2/kt3 reload, nt stores. HBM read stream stays continuously fed.

__global__ __launch_bounds__(256, 3) void out_gemm_k(
    const float* __restrict__ x, const unsigned short* __restrict__ wsB,
    const float* __restrict__ bo, const int* __restrict__ flags,
    float* __restrict__ out)
{
    __shared__ char As[4][4096];    // [kt][32 rows][128 B] (64 bf16 k, swizzled 16B slots)

    const int tid  = threadIdx.x;
    const int wave = tid >> 6;
    const int lane = tid & 63;
    const int rl   = lane & 15;
    const int hi   = lane >> 4;
    const int wcol = wave * 64;

    const int ar = tid >> 3;          // staging row 0..31
    const int aq = tid & 7;           // staging k-octet 0..7
    const int swr = (aq ^ (ar & 7)) << 4;

    const char* gB = (const char*)wsB + wave * 8192 + lane * 16;

    f32x4 av0, av1, av2, av3, av4, av5, av6, av7;
    int4 flg0, flg1, nf0, nf1;

#define ISSUE_AV(T) do {                                                   \
        int rr = (T) * 32 + ar; if (rr >= NN) rr = NN - 1;                 \
        const float* p_ = x + (size_t)rr * HID + aq * 8;                   \
        av0 = __builtin_nontemporal_load((const f32x4*)(p_));              \
        av1 = __builtin_nontemporal_load((const f32x4*)(p_ + 4));          \
        av2 = __builtin_nontemporal_load((const f32x4*)(p_ + 64));         \
        av3 = __builtin_nontemporal_load((const f32x4*)(p_ + 68));         \
        av4 = __builtin_nontemporal_load((const f32x4*)(p_ + 128));        \
        av5 = __builtin_nontemporal_load((const f32x4*)(p_ + 132));        \
        av6 = __builtin_nontemporal_load((const f32x4*)(p_ + 192));        \
        av7 = __builtin_nontemporal_load((const f32x4*)(p_ + 196));        \
    } while (0)

#define ISSUE_FLG(T, F0, F1) do {                                          \
        F0 = *(const int4*)(flags + (T) * 32 + hi * 4);                    \
        F1 = *(const int4*)(flags + (T) * 32 + 16 + hi * 4);               \
    } while (0)   /* tail over-read stays inside ws; rows>=NN masked at store */

#define WRT(KT, LO, HI4) do {                                              \
        bf16x8 w_;                                                         \
        w_[0] = f2bf(LO[0]); w_[1] = f2bf(LO[1]);                          \
        w_[2] = f2bf(LO[2]); w_[3] = f2bf(LO[3]);                          \
        w_[4] = f2bf(HI4[0]); w_[5] = f2bf(HI4[1]);                        \
        w_[6] = f2bf(HI4[2]); w_[7] = f2bf(HI4[3]);                        \
        *(bf16x8*)(As[KT] + ar * 128 + swr) = w_;                          \
    } while (0)

#define LOAD_B(DST, KT) do {                                               \
        _Pragma("unroll")                                                  \
        for (int n_ = 0; n_ < 4; ++n_) {                                   \
            DST[n_][0] = *(const bf16x8*)(gB + (KT) * 32768 + n_ * 2048);  \
            DST[n_][1] = *(const bf16x8*)(gB + (KT) * 32768 + n_ * 2048 + 1024); \
        }                                                                  \
    } while (0)

#define STEP(KT, B) do {                                                   \
        _Pragma("unroll")                                                  \
        for (int kk_ = 0; kk_ < 2; ++kk_) {                                \
            const int sw_ = ((((kk_ << 2) + hi) ^ (rl & 7)) << 4);         \
            bf16x8 af0_ = *(const bf16x8*)(As[KT] + (rl) * 128 + sw_);     \
            bf16x8 af1_ = *(const bf16x8*)(As[KT] + (16 + rl) * 128 + sw_);\
            _Pragma("unroll")                                              \
            for (int n_ = 0; n_ < 4; ++n_) {                               \
                acc[0][n_] = __builtin_amdgcn_mfma_f32_16x16x32_bf16(af0_, B[n_][kk_], acc[0][n_], 0, 0, 0); \
                acc[1][n_] = __builtin_amdgcn_mfma_f32_16x16x32_bf16(af1_, B[n_][kk_], acc[1][n_], 0, 0, 0); \
            }                                                              \
        }                                                                  \
    } while (0)

    float bov[4];
    #pragma unroll
    for (int n = 0; n < 4; ++n) bov[n] = bo[wcol + n * 16 + rl];

    int t = blockIdx.x;
    ISSUE_AV(t);
    ISSUE_FLG(t, flg0, flg1);

    bf16x8 bA[4][2], bB[4][2];
    f32x4 acc[2][4];

    #pragma unroll 1
    for (; t < NTILES; t += GRID_GEMM) {
        asm volatile("" ::: "memory");
        __builtin_amdgcn_s_barrier();          // As reuse guard (no drain needed)

        WRT(0, av0, av1); WRT(1, av2, av3);    // consume av -> LDS (auto vmcnt waits)
        WRT(2, av4, av5); WRT(3, av6, av7);

        LOAD_B(bA, 0);                         // L2 image, needed first after barrier
        LOAD_B(bB, 1);
        __builtin_amdgcn_sched_barrier(0);     // pin B-issue before next-tile HBM issue

        const int tn = t + GRID_GEMM;
        if (tn < NTILES) {                     // uniform branch
            ISSUE_AV(tn);                      // HBM reads fly across the barrier
            ISSUE_FLG(tn, nf0, nf1);
        }

        asm volatile("s_waitcnt lgkmcnt(0)" ::: "memory");   // LDS visible, vmcnt NOT drained
        __builtin_amdgcn_s_barrier();

        #pragma unroll
        for (int m = 0; m < 2; ++m)
            #pragma unroll
            for (int n = 0; n < 4; ++n)
                acc[m][n] = (f32x4){0.f, 0.f, 0.f, 0.f};

        STEP(0, bA);
        STEP(1, bB);
        LOAD_B(bA, 2);                         // WAR on bA regs orders after STEP(0)
        LOAD_B(bB, 3);
        STEP(2, bA);
        STEP(3, bB);

        // ---- epilogue: out[r] = (flags[r]==MAGIC) ? acc + bo : bo ----
        const int row0 = t * 32;
        {
            const int fl0[4] = {flg0.x, flg0.y, flg0.z, flg0.w};
            const int fl1[4] = {flg1.x, flg1.y, flg1.z, flg1.w};
            #pragma unroll
            for (int j = 0; j < 4; ++j) {
                const int r0 = row0 + hi * 4 + j;            // m=0 rows
                if (r0 < NN) {
                    const float msk = (fl0[j] == FLAG_MAGIC) ? 1.f : 0.f;
                    float* orow = out + (size_t)r0 * HID + wcol + rl;
                    #pragma unroll
                    for (int n = 0; n < 4; ++n)
                        __builtin_nontemporal_store(fmaf(msk, acc[0][n][j], bov[n]), &orow[n * 16]);
                }
                const int r1 = row0 + 16 + hi * 4 + j;       // m=1 rows
                if (r1 < NN) {
                    const float msk = (fl1[j] == FLAG_MAGIC) ? 1.f : 0.f;
                    float* orow = out + (size_t)r1 * HID + wcol + rl;
                    #pragma unroll
                    for (int n = 0; n < 4; ++n)
                        __builtin_nontemporal_store(fmaf(msk, acc[1][n][j], bov[n]), &orow[n * 16]);
                }
            }
        }
        flg0 = nf0; flg1 = nf1;
    }

#undef ISSUE_AV
#undef ISSUE_FLG
#undef WRT
#undef LOAD_B
#undef STEP
}

// ---------------- launch ----------------

extern "C" void kernel_launch(void* const* d_in, const int* in_sizes, int n_in,
                              void* d_out, int out_size, void* d_ws, size_t ws_size,
                              hipStream_t stream) {
    const float* x   = (const float*)d_in[0];
    const int*   ei  = (const int*)d_in[1];
    const float* Wv  = (const float*)d_in[5];
    const float* Wo  = (const float*)d_in[7];
    const float* bo  = (const float*)d_in[8];
    float* out = (float*)d_out;

    unsigned short* wsB = (unsigned short*)d_ws;            // 128 KiB fragment image
    int* flags = (int*)((char*)d_ws + 4 * 32768);

    prep_k<<<NBLK_FLAG + HID, 256, 0, stream>>>(ei, flags, Wv, Wo, wsB);

    out_gemm_k<<<GRID_GEMM, 256, 0, stream>>>(x, wsB, bo, flags, out);
}

// Round 8
// 36.528 us; speedup vs baseline: 1.6201x; 1.6201x over previous
//
#include <hip/hip_runtime.h>
#include <hip/hip_bf16.h>

#define NN 50000
#define NE 320000
#define HID 256
#define NBLK_FLAG 1250            // ceil(NE/256)
#define FLAG_MAGIC 0x7F3A9C51

typedef __attribute__((ext_vector_type(8))) short bf16x8;   // 8 bf16 = 4 VGPR
typedef __attribute__((ext_vector_type(4))) float f32x4;

static __device__ __forceinline__ short f2bf(float f) {
    union { __hip_bfloat16 h; short s; } u;
    u.h = __float2bfloat16(f);     // RNE; pairs pack to v_cvt_pk_bf16_f32
    return u.s;
}

// ---------------- prep: flags scatter + W2=Wv@Wo (bf16 fragment image) ----------------
// wsB layout = per-wave MFMA B fragments, coalesced:
//   byte off = kt*32768 + c16*2048 + kk*1024 + h*256 + rl*16 + e*2
// where k = kt*64 + kk*32 + h*8 + e, col = c16*16 + rl.
// Flags: idempotent FLAG_MAGIC scatter (inputs fixed); 0xAA poison never matches.
__global__ void prep_k(const int* __restrict__ ei, int* __restrict__ flags,
                       const float* __restrict__ Wv, const float* __restrict__ Wo,
                       unsigned short* __restrict__ wsB) {
    const int b = blockIdx.x;
    if (b < NBLK_FLAG) {
        __shared__ int nz;
        if (threadIdx.x == 0) nz = 0;
        __syncthreads();
        unsigned hv = ((const unsigned*)ei)[2 * threadIdx.x + 1];
        if (hv != 0u) nz = 1;              // benign same-value race
        __syncthreads();
        const int is64 = (nz == 0);        // int64 => high dwords all zero
        const int e = b * 256 + threadIdx.x;
        if (e < NE) {
            int t = is64 ? ei[2 * (NE + e)] : ei[NE + e];
            if (t >= 0 && t < NN) flags[t] = FLAG_MAGIC;   // benign same-value race
        }
    } else {
        const int i = b - NBLK_FLAG;       // W2 row == GEMM k, 0..255 (one row per block)
        const int j = threadIdx.x;         // col
        const float* wv = Wv + i * HID;    // wave-uniform scalar loads
        float s0 = 0.f, s1 = 0.f, s2 = 0.f, s3 = 0.f;
        #pragma unroll 8
        for (int k = 0; k < HID; k += 4) {
            s0 = fmaf(wv[k + 0], Wo[(k + 0) * HID + j], s0);
            s1 = fmaf(wv[k + 1], Wo[(k + 1) * HID + j], s1);
            s2 = fmaf(wv[k + 2], Wo[(k + 2) * HID + j], s2);
            s3 = fmaf(wv[k + 3], Wo[(k + 3) * HID + j], s3);
        }
        const float acc = (s0 + s1) + (s2 + s3);
        const int kt = i >> 6, kp = i & 63;
        const int kk = kp >> 5, h = (kp >> 3) & 3, e = kp & 7;
        wsB[(kt * 32768 + (j >> 4) * 2048 + kk * 1024 + h * 256 + (j & 15) * 16 + e * 2) >> 1]
            = (unsigned short)f2bf(acc);
    }
}

// ---------------- out = mask ? x @ W2 + bo : bo  (bf16 MFMA) ----------------
// 256 threads (4 waves), tile 32 rows x 256 cols, grid 1563. All A loads upfront,
// one pre-MFMA sync, B ping-pong from L2 image. Epilogue transposes acc through
// LDS (union with A-tile, 16.6 KB) so the out stream is full-row dwordx4 stores.

#define CS_STRIDE 260             // f32 per staged row (+4 pad: 2-way bank conflicts only)

__global__ __launch_bounds__(256) void out_gemm_k(
    const float* __restrict__ x, const unsigned short* __restrict__ wsB,
    const float* __restrict__ bo, const int* __restrict__ flags,
    float* __restrict__ out)
{
    __shared__ char lds[16640];   // phase 1: A tiles 4x4KB; phase 2: 16 x 260 f32 C-stage
    float* Cs = (float*)lds;

    const int tid  = threadIdx.x;
    const int wave = tid >> 6;
    const int lane = tid & 63;
    const int rl   = lane & 15;
    const int hi   = lane >> 4;
    const int row0 = blockIdx.x * 32;
    const int wcol = wave * 64;

    // A staging map: thread -> (row ar = tid>>3, k-octet aq = tid&7)
    const int ar = tid >> 3;          // 0..31
    const int aq = tid & 7;           // 0..7  (8 k-floats each)
    int grow = row0 + ar; if (grow >= NN) grow = NN - 1;   // clamp tail (store masks)
    const float* asrc = x + (size_t)grow * HID + aq * 8;
    const int swr = (aq ^ (ar & 7)) << 4;                  // swizzled slot byte offset

    // ---- issue ALL A loads upfront (8 dwordx4/thread = 32KB tile in flight) ----
    f32x4 av[8];
    #pragma unroll
    for (int kt = 0; kt < 4; ++kt) {
        av[2 * kt]     = *(const f32x4*)(asrc + kt * 64);
        av[2 * kt + 1] = *(const f32x4*)(asrc + kt * 64 + 4);
    }

    // ---- B kt0 + flags + bo early ----
    const char* gB = (const char*)wsB + wave * 8192 + lane * 16;
    bf16x8 bA[4][2], bB[4][2];
    #pragma unroll
    for (int n = 0; n < 4; ++n)
        #pragma unroll
        for (int kk = 0; kk < 2; ++kk)
            bA[n][kk] = *(const bf16x8*)(gB + n * 2048 + kk * 1024);

    int4 flg[2];
    #pragma unroll
    for (int m = 0; m < 2; ++m)
        flg[m] = *(const int4*)(flags + row0 + m * 16 + hi * 4);  // tail over-read in-ws; masked at store
    float bov[4];
    #pragma unroll
    for (int n = 0; n < 4; ++n) bov[n] = bo[wcol + n * 16 + rl];

    // ---- convert + write 4 LDS A-buffers, single sync ----
    #pragma unroll
    for (int kt = 0; kt < 4; ++kt) {
        const f32x4 v0 = av[2 * kt], v1 = av[2 * kt + 1];
        bf16x8 w;
        w[0] = f2bf(v0[0]); w[1] = f2bf(v0[1]); w[2] = f2bf(v0[2]); w[3] = f2bf(v0[3]);
        w[4] = f2bf(v1[0]); w[5] = f2bf(v1[1]); w[6] = f2bf(v1[2]); w[7] = f2bf(v1[3]);
        *(bf16x8*)(lds + kt * 4096 + ar * 128 + swr) = w;
    }
    __syncthreads();

    f32x4 acc[2][4];
    #pragma unroll
    for (int m = 0; m < 2; ++m)
        #pragma unroll
        for (int n = 0; n < 4; ++n)
            acc[m][n] = (f32x4){0.f, 0.f, 0.f, 0.f};

    // ---- MFMA loop, B ping-pong prefetch ----
    auto step = [&](const int kt, bf16x8 (&bcur)[4][2], bf16x8 (&bnext)[4][2], const bool pf) {
        if (pf) {
            #pragma unroll
            for (int n = 0; n < 4; ++n)
                #pragma unroll
                for (int kk = 0; kk < 2; ++kk)
                    bnext[n][kk] = *(const bf16x8*)(gB + (kt + 1) * 32768 + n * 2048 + kk * 1024);
        }
        #pragma unroll
        for (int kk = 0; kk < 2; ++kk) {
            bf16x8 af[2];
            #pragma unroll
            for (int m = 0; m < 2; ++m)
                af[m] = *(const bf16x8*)(lds + kt * 4096 + (m * 16 + rl) * 128
                                         + ((((kk << 2) + hi) ^ (rl & 7)) << 4));
            #pragma unroll
            for (int m = 0; m < 2; ++m)
                #pragma unroll
                for (int n = 0; n < 4; ++n)
                    acc[m][n] = __builtin_amdgcn_mfma_f32_16x16x32_bf16(af[m], bcur[n][kk], acc[m][n], 0, 0, 0);
        }
    };
    step(0, bA, bB, true);
    step(1, bB, bA, true);
    step(2, bA, bB, true);
    step(3, bB, bA, false);

    // ---- epilogue: stage masked+biased acc through LDS; full-row dwordx4 stores ----
    #pragma unroll
    for (int h2 = 0; h2 < 2; ++h2) {
        __syncthreads();               // h2=0: A-reads done; h2=1: prev Cs reads done
        const int fl[4] = {flg[h2].x, flg[h2].y, flg[h2].z, flg[h2].w};
        #pragma unroll
        for (int j = 0; j < 4; ++j) {
            const float msk = (fl[j] == FLAG_MAGIC) ? 1.f : 0.f;
            float* crow = Cs + (hi * 4 + j) * CS_STRIDE + wcol + rl;
            #pragma unroll
            for (int n = 0; n < 4; ++n)
                crow[n * 16] = fmaf(msk, acc[h2][n][j], bov[n]);
        }
        __syncthreads();
        #pragma unroll
        for (int i = 0; i < 4; ++i) {
            const int rloc = wave * 4 + i;
            const f32x4 v = *(const f32x4*)(Cs + rloc * CS_STRIDE + lane * 4);
            const int r = row0 + h2 * 16 + rloc;
            if (r < NN)
                *(f32x4*)(out + (size_t)r * HID + lane * 4) = v;
        }
    }
}

// ---------------- launch ----------------

extern "C" void kernel_launch(void* const* d_in, const int* in_sizes, int n_in,
                              void* d_out, int out_size, void* d_ws, size_t ws_size,
                              hipStream_t stream) {
    const float* x   = (const float*)d_in[0];
    const int*   ei  = (const int*)d_in[1];
    const float* Wv  = (const float*)d_in[5];
    const float* Wo  = (const float*)d_in[7];
    const float* bo  = (const float*)d_in[8];
    float* out = (float*)d_out;

    unsigned short* wsB = (unsigned short*)d_ws;            // 128 KiB fragment image
    int* flags = (int*)((char*)d_ws + 4 * 32768);

    prep_k<<<NBLK_FLAG + HID, 256, 0, stream>>>(ei, flags, Wv, Wo, wsB);

    dim3 grid((NN + 31) / 32);
    out_gemm_k<<<grid, 256, 0, stream>>>(x, wsB, bo, flags, out);
}

// Round 9
// 35.927 us; speedup vs baseline: 1.6473x; 1.0167x over previous
//
#include <hip/hip_runtime.h>
#include <hip/hip_bf16.h>

#define NN 50000
#define NE 320000
#define HID 256
#define NBLK_FLAG 1250            // ceil(NE/256)
#define FLAG_MAGIC 0x7F3A9C51

typedef __attribute__((ext_vector_type(8))) short bf16x8;   // 8 bf16 = 4 VGPR
typedef __attribute__((ext_vector_type(4))) float f32x4;

static __device__ __forceinline__ short f2bf(float f) {
    union { __hip_bfloat16 h; short s; } u;
    u.h = __float2bfloat16(f);     // RNE; pairs pack to v_cvt_pk_bf16_f32
    return u.s;
}

// ---------------- prep: flags scatter + W2=Wv@Wo (bf16 fragment image) ----------------
// wsB layout = per-wave MFMA B fragments, coalesced:
//   byte off = kt*32768 + c16*2048 + kk*1024 + h*256 + rl*16 + e*2
// where k = kt*64 + kk*32 + h*8 + e, col = c16*16 + rl.
// Flags: idempotent FLAG_MAGIC scatter (inputs fixed); 0xAA poison never matches.
__global__ void prep_k(const int* __restrict__ ei, int* __restrict__ flags,
                       const float* __restrict__ Wv, const float* __restrict__ Wo,
                       unsigned short* __restrict__ wsB) {
    const int b = blockIdx.x;
    if (b < NBLK_FLAG) {
        __shared__ int nz;
        if (threadIdx.x == 0) nz = 0;
        __syncthreads();
        unsigned hv = ((const unsigned*)ei)[2 * threadIdx.x + 1];
        if (hv != 0u) nz = 1;              // benign same-value race
        __syncthreads();
        const int is64 = (nz == 0);        // int64 => high dwords all zero
        const int e = b * 256 + threadIdx.x;
        if (e < NE) {
            int t = is64 ? ei[2 * (NE + e)] : ei[NE + e];
            if (t >= 0 && t < NN) flags[t] = FLAG_MAGIC;   // benign same-value race
        }
    } else {
        const int i = b - NBLK_FLAG;       // W2 row == GEMM k, 0..255 (one row per block)
        const int j = threadIdx.x;         // col
        const float* wv = Wv + i * HID;    // wave-uniform scalar loads
        float s0 = 0.f, s1 = 0.f, s2 = 0.f, s3 = 0.f;
        #pragma unroll 8
        for (int k = 0; k < HID; k += 4) {
            s0 = fmaf(wv[k + 0], Wo[(k + 0) * HID + j], s0);
            s1 = fmaf(wv[k + 1], Wo[(k + 1) * HID + j], s1);
            s2 = fmaf(wv[k + 2], Wo[(k + 2) * HID + j], s2);
            s3 = fmaf(wv[k + 3], Wo[(k + 3) * HID + j], s3);
        }
        const float acc = (s0 + s1) + (s2 + s3);
        const int kt = i >> 6, kp = i & 63;
        const int kk = kp >> 5, h = (kp >> 3) & 3, e = kp & 7;
        wsB[(kt * 32768 + (j >> 4) * 2048 + kk * 1024 + h * 256 + (j & 15) * 16 + e * 2) >> 1]
            = (unsigned short)f2bf(acc);
    }
}

// ---------------- out = mask ? x @ W2 + bo : bo  (bf16 MFMA) ----------------
// 256 threads (4 waves), tile 64 rows x 256 cols, grid 782. A staged in two
// 8-load bursts (VGPR control), one pre-MFMA sync, B ping-pong from the L2
// fragment image (wave-exclusive col slices). Epilogue transposes acc through
// LDS in two 32-row halves; each store instruction writes one full 1KB row.

#define CS_STRIDE 260             // f32 per staged row (+4: bank-conflict-free-ish)

__global__ __launch_bounds__(256) void out_gemm_k(
    const float* __restrict__ x, const unsigned short* __restrict__ wsB,
    const float* __restrict__ bo, const int* __restrict__ flags,
    float* __restrict__ out)
{
    __shared__ char lds[33280];   // phase 1: A tiles 4x8KB (32KB); phase 2: 32 x 260 f32 C-stage
    float* Cs = (float*)lds;

    const int tid  = threadIdx.x;
    const int wave = tid >> 6;
    const int lane = tid & 63;
    const int rl   = lane & 15;
    const int hi   = lane >> 4;
    const int row0 = blockIdx.x * 64;
    const int wcol = wave * 64;

    // A staging map: thread -> (row ar = tid>>2, k-16-chunk aq = tid&3)
    const int ar = tid >> 2;          // 0..63
    const int aq = tid & 3;           // 0..3  (16 k-floats each)
    int grow = row0 + ar; if (grow >= NN) grow = NN - 1;   // clamp tail (store masks)
    const float* asrc = x + (size_t)grow * HID + aq * 16;
    const int s0 = ((2 * aq)     ^ (ar & 7)) << 4;         // swizzled slot bytes
    const int s1 = ((2 * aq + 1) ^ (ar & 7)) << 4;

    // flags + bias early
    int4 flg[4];
    #pragma unroll
    for (int m = 0; m < 4; ++m)
        flg[m] = *(const int4*)(flags + row0 + m * 16 + hi * 4);  // tail over-read in-ws; masked at store
    float bov[4];
    #pragma unroll
    for (int n = 0; n < 4; ++n) bov[n] = bo[wcol + n * 16 + rl];

    // ---- A burst 0 (kt0,kt1): 8 dwordx4 in flight, cvt, LDS write ----
    {
        f32x4 v[8];
        #pragma unroll
        for (int kt = 0; kt < 2; ++kt)
            #pragma unroll
            for (int q = 0; q < 4; ++q)
                v[kt * 4 + q] = *(const f32x4*)(asrc + kt * 64 + q * 4);
        #pragma unroll
        for (int kt = 0; kt < 2; ++kt) {
            bf16x8 w0, w1;
            const f32x4 a0 = v[kt * 4], a1 = v[kt * 4 + 1], a2 = v[kt * 4 + 2], a3 = v[kt * 4 + 3];
            w0[0] = f2bf(a0[0]); w0[1] = f2bf(a0[1]); w0[2] = f2bf(a0[2]); w0[3] = f2bf(a0[3]);
            w0[4] = f2bf(a1[0]); w0[5] = f2bf(a1[1]); w0[6] = f2bf(a1[2]); w0[7] = f2bf(a1[3]);
            w1[0] = f2bf(a2[0]); w1[1] = f2bf(a2[1]); w1[2] = f2bf(a2[2]); w1[3] = f2bf(a2[3]);
            w1[4] = f2bf(a3[0]); w1[5] = f2bf(a3[1]); w1[6] = f2bf(a3[2]); w1[7] = f2bf(a3[3]);
            *(bf16x8*)(lds + kt * 8192 + ar * 128 + s0) = w0;
            *(bf16x8*)(lds + kt * 8192 + ar * 128 + s1) = w1;
        }
    }
    // ---- A burst 1 (kt2,kt3) ----
    {
        f32x4 v[8];
        #pragma unroll
        for (int kt = 0; kt < 2; ++kt)
            #pragma unroll
            for (int q = 0; q < 4; ++q)
                v[kt * 4 + q] = *(const f32x4*)(asrc + (kt + 2) * 64 + q * 4);
        #pragma unroll
        for (int kt = 0; kt < 2; ++kt) {
            bf16x8 w0, w1;
            const f32x4 a0 = v[kt * 4], a1 = v[kt * 4 + 1], a2 = v[kt * 4 + 2], a3 = v[kt * 4 + 3];
            w0[0] = f2bf(a0[0]); w0[1] = f2bf(a0[1]); w0[2] = f2bf(a0[2]); w0[3] = f2bf(a0[3]);
            w0[4] = f2bf(a1[0]); w0[5] = f2bf(a1[1]); w0[6] = f2bf(a1[2]); w0[7] = f2bf(a1[3]);
            w1[0] = f2bf(a2[0]); w1[1] = f2bf(a2[1]); w1[2] = f2bf(a2[2]); w1[3] = f2bf(a2[3]);
            w1[4] = f2bf(a3[0]); w1[5] = f2bf(a3[1]); w1[6] = f2bf(a3[2]); w1[7] = f2bf(a3[3]);
            *(bf16x8*)(lds + (kt + 2) * 8192 + ar * 128 + s0) = w0;
            *(bf16x8*)(lds + (kt + 2) * 8192 + ar * 128 + s1) = w1;
        }
    }
    __syncthreads();

    const char* gB = (const char*)wsB + wave * 8192 + lane * 16;
    f32x4 acc[4][4];
    #pragma unroll
    for (int m = 0; m < 4; ++m)
        #pragma unroll
        for (int n = 0; n < 4; ++n)
            acc[m][n] = (f32x4){0.f, 0.f, 0.f, 0.f};

    bf16x8 bA[4][2], bB[4][2];
    #pragma unroll
    for (int n = 0; n < 4; ++n)
        #pragma unroll
        for (int kk = 0; kk < 2; ++kk)
            bA[n][kk] = *(const bf16x8*)(gB + n * 2048 + kk * 1024);

    // ---- MFMA loop, B ping-pong prefetch ----
    auto step = [&](const int kt, bf16x8 (&bcur)[4][2], bf16x8 (&bnext)[4][2], const bool pf) {
        if (pf) {
            #pragma unroll
            for (int n = 0; n < 4; ++n)
                #pragma unroll
                for (int kk = 0; kk < 2; ++kk)
                    bnext[n][kk] = *(const bf16x8*)(gB + (kt + 1) * 32768 + n * 2048 + kk * 1024);
        }
        #pragma unroll
        for (int kk = 0; kk < 2; ++kk) {
            bf16x8 af[4];
            #pragma unroll
            for (int m = 0; m < 4; ++m)
                af[m] = *(const bf16x8*)(lds + kt * 8192 + (m * 16 + rl) * 128
                                         + ((((kk << 2) + hi) ^ (rl & 7)) << 4));
            #pragma unroll
            for (int m = 0; m < 4; ++m)
                #pragma unroll
                for (int n = 0; n < 4; ++n)
                    acc[m][n] = __builtin_amdgcn_mfma_f32_16x16x32_bf16(af[m], bcur[n][kk], acc[m][n], 0, 0, 0);
        }
    };
    step(0, bA, bB, true);
    step(1, bB, bA, true);
    step(2, bA, bB, true);
    step(3, bB, bA, false);

    // ---- epilogue: two 32-row halves through LDS; full-row dwordx4 stores ----
    #pragma unroll
    for (int h2 = 0; h2 < 2; ++h2) {
        __syncthreads();               // h2=0: A-reads done; h2=1: prev Cs reads done
        #pragma unroll
        for (int mm = 0; mm < 2; ++mm) {
            const int m = 2 * h2 + mm;
            const int fl[4] = {flg[m].x, flg[m].y, flg[m].z, flg[m].w};
            #pragma unroll
            for (int j = 0; j < 4; ++j) {
                const float msk = (fl[j] == FLAG_MAGIC) ? 1.f : 0.f;
                float* crow = Cs + (mm * 16 + hi * 4 + j) * CS_STRIDE + wcol + rl;
                #pragma unroll
                for (int n = 0; n < 4; ++n)
                    crow[n * 16] = fmaf(msk, acc[m][n][j], bov[n]);
            }
        }
        __syncthreads();
        #pragma unroll
        for (int i = 0; i < 8; ++i) {
            const int rloc = wave * 8 + i;                     // one full row per wave-instr
            const f32x4 v = *(const f32x4*)(Cs + rloc * CS_STRIDE + lane * 4);
            const int g = row0 + h2 * 32 + rloc;
            if (g < NN)
                *(f32x4*)(out + (size_t)g * HID + lane * 4) = v;
        }
    }
}

// ---------------- launch ----------------

extern "C" void kernel_launch(void* const* d_in, const int* in_sizes, int n_in,
                              void* d_out, int out_size, void* d_ws, size_t ws_size,
                              hipStream_t stream) {
    const float* x   = (const float*)d_in[0];
    const int*   ei  = (const int*)d_in[1];
    const float* Wv  = (const float*)d_in[5];
    const float* Wo  = (const float*)d_in[7];
    const float* bo  = (const float*)d_in[8];
    float* out = (float*)d_out;

    unsigned short* wsB = (unsigned short*)d_ws;            // 128 KiB fragment image
    int* flags = (int*)((char*)d_ws + 4 * 32768);

    prep_k<<<NBLK_FLAG + HID, 256, 0, stream>>>(ei, flags, Wv, Wo, wsB);

    dim3 grid((NN + 63) / 64);
    out_gemm_k<<<grid, 256, 0, stream>>>(x, wsB, bo, flags, out);
}

// Round 10
// 33.313 us; speedup vs baseline: 1.7765x; 1.0785x over previous
//
#include <hip/hip_runtime.h>
#include <hip/hip_bf16.h>

#define NN 50000
#define NE 320000
#define HID 256
#define NBLK_FLAG 1250            // ceil(NE/256)
#define FLAG_MAGIC 0x7F3A9C51

typedef __attribute__((ext_vector_type(8))) short bf16x8;   // 8 bf16 = 4 VGPR
typedef __attribute__((ext_vector_type(4))) float f32x4;

static __device__ __forceinline__ short f2bf(float f) {
    union { __hip_bfloat16 h; short s; } u;
    u.h = __float2bfloat16(f);     // RNE; pairs pack to v_cvt_pk_bf16_f32
    return u.s;
}

// ---------------- prep: flags scatter + W2=Wv@Wo (bf16 fragment image) ----------------
// wsB layout = per-wave MFMA B fragments, coalesced:
//   byte off = kt*32768 + c16*2048 + kk*1024 + h*256 + rl*16 + e*2
// where k = kt*64 + kk*32 + h*8 + e, col = c16*16 + rl.
// Flags: idempotent FLAG_MAGIC scatter (inputs fixed); 0xAA poison never matches.
__global__ void prep_k(const int* __restrict__ ei, int* __restrict__ flags,
                       const float* __restrict__ Wv, const float* __restrict__ Wo,
                       unsigned short* __restrict__ wsB) {
    const int b = blockIdx.x;
    if (b < NBLK_FLAG) {
        __shared__ int nz;
        if (threadIdx.x == 0) nz = 0;
        __syncthreads();
        unsigned hv = ((const unsigned*)ei)[2 * threadIdx.x + 1];
        if (hv != 0u) nz = 1;              // benign same-value race
        __syncthreads();
        const int is64 = (nz == 0);        // int64 => high dwords all zero
        const int e = b * 256 + threadIdx.x;
        if (e < NE) {
            int t = is64 ? ei[2 * (NE + e)] : ei[NE + e];
            if (t >= 0 && t < NN) flags[t] = FLAG_MAGIC;   // benign same-value race
        }
    } else {
        const int i = b - NBLK_FLAG;       // W2 row == GEMM k, 0..255 (one row per block)
        const int j = threadIdx.x;         // col
        const float* wv = Wv + i * HID;    // wave-uniform scalar loads
        float s0 = 0.f, s1 = 0.f, s2 = 0.f, s3 = 0.f;
        #pragma unroll 8
        for (int k = 0; k < HID; k += 4) {
            s0 = fmaf(wv[k + 0], Wo[(k + 0) * HID + j], s0);
            s1 = fmaf(wv[k + 1], Wo[(k + 1) * HID + j], s1);
            s2 = fmaf(wv[k + 2], Wo[(k + 2) * HID + j], s2);
            s3 = fmaf(wv[k + 3], Wo[(k + 3) * HID + j], s3);
        }
        const float acc = (s0 + s1) + (s2 + s3);
        const int kt = i >> 6, kp = i & 63;
        const int kk = kp >> 5, h = (kp >> 3) & 3, e = kp & 7;
        wsB[(kt * 32768 + (j >> 4) * 2048 + kk * 1024 + h * 256 + (j & 15) * 16 + e * 2) >> 1]
            = (unsigned short)f2bf(acc);
    }
}

// ---------------- out = mask ? x @ W2 + bo : bo  (bf16 MFMA, VGPR-diet) ----------------
// 256 threads (4 waves), tile 32 rows x 256 cols, grid 1563. Target <=128 VGPR so
// 4 blocks/CU (16 waves) co-reside: acc 32 + single-buffer B 32 + av 32 transient.
// All A loads upfront, one pre-MFMA sync, flags loaded late, LDS-transpose stores.

#define CS_STRIDE 260             // f32 per staged row (+4 pad)

__global__ __launch_bounds__(256, 4) void out_gemm_k(
    const float* __restrict__ x, const unsigned short* __restrict__ wsB,
    const float* __restrict__ bo, const int* __restrict__ flags,
    float* __restrict__ out)
{
    __shared__ char lds[16640];   // phase 1: A tiles 4x4KB; phase 2: 16 x 260 f32 C-stage
    float* Cs = (float*)lds;

    const int tid  = threadIdx.x;
    const int wave = tid >> 6;
    const int lane = tid & 63;
    const int rl   = lane & 15;
    const int hi   = lane >> 4;
    const int row0 = blockIdx.x * 32;
    const int wcol = wave * 64;

    // A staging map: thread -> (row ar = tid>>3, k-octet aq = tid&7)
    const int ar = tid >> 3;          // 0..31
    const int aq = tid & 7;           // 0..7  (8 k-floats each)
    int grow = row0 + ar; if (grow >= NN) grow = NN - 1;   // clamp tail (store masks)
    const float* asrc = x + (size_t)grow * HID + aq * 8;
    const int swr = (aq ^ (ar & 7)) << 4;                  // swizzled slot byte offset

    // ---- issue ALL A loads upfront (8 dwordx4/thread = 32KB tile in flight) ----
    f32x4 av[8];
    #pragma unroll
    for (int kt = 0; kt < 4; ++kt) {
        av[2 * kt]     = *(const f32x4*)(asrc + kt * 64);
        av[2 * kt + 1] = *(const f32x4*)(asrc + kt * 64 + 4);
    }

    // ---- pre-issue B kt0 (single buffer, 32 VGPR) + bias ----
    const char* gB = (const char*)wsB + wave * 8192 + lane * 16;
    bf16x8 bfrag[4][2];
    #pragma unroll
    for (int n = 0; n < 4; ++n)
        #pragma unroll
        for (int kk = 0; kk < 2; ++kk)
            bfrag[n][kk] = *(const bf16x8*)(gB + n * 2048 + kk * 1024);
    float bov[4];
    #pragma unroll
    for (int n = 0; n < 4; ++n) bov[n] = bo[wcol + n * 16 + rl];

    // ---- convert + write 4 LDS A-buffers, single sync ----
    #pragma unroll
    for (int kt = 0; kt < 4; ++kt) {
        const f32x4 v0 = av[2 * kt], v1 = av[2 * kt + 1];
        bf16x8 w;
        w[0] = f2bf(v0[0]); w[1] = f2bf(v0[1]); w[2] = f2bf(v0[2]); w[3] = f2bf(v0[3]);
        w[4] = f2bf(v1[0]); w[5] = f2bf(v1[1]); w[6] = f2bf(v1[2]); w[7] = f2bf(v1[3]);
        *(bf16x8*)(lds + kt * 4096 + ar * 128 + swr) = w;
    }
    __syncthreads();

    f32x4 acc[2][4];
    #pragma unroll
    for (int m = 0; m < 2; ++m)
        #pragma unroll
        for (int n = 0; n < 4; ++n)
            acc[m][n] = (f32x4){0.f, 0.f, 0.f, 0.f};

    int4 flg[2];

    // ---- MFMA loop, single-buffered B (load kt+1 after kt's last use) ----
    #pragma unroll
    for (int kt = 0; kt < 4; ++kt) {
        #pragma unroll
        for (int kk = 0; kk < 2; ++kk) {
            bf16x8 af[2];
            #pragma unroll
            for (int m = 0; m < 2; ++m)
                af[m] = *(const bf16x8*)(lds + kt * 4096 + (m * 16 + rl) * 128
                                         + ((((kk << 2) + hi) ^ (rl & 7)) << 4));
            #pragma unroll
            for (int m = 0; m < 2; ++m)
                #pragma unroll
                for (int n = 0; n < 4; ++n)
                    acc[m][n] = __builtin_amdgcn_mfma_f32_16x16x32_bf16(af[m], bfrag[n][kk], acc[m][n], 0, 0, 0);
        }
        if (kt < 3) {
            #pragma unroll
            for (int n = 0; n < 4; ++n)
                #pragma unroll
                for (int kk = 0; kk < 2; ++kk)
                    bfrag[n][kk] = *(const bf16x8*)(gB + (kt + 1) * 32768 + n * 2048 + kk * 1024);
        } else {
            #pragma unroll
            for (int m = 0; m < 2; ++m)
                flg[m] = *(const int4*)(flags + row0 + m * 16 + hi * 4);  // late; tail over-read in-ws
        }
    }

    // ---- epilogue: stage masked+biased acc through LDS; full-row dwordx4 stores ----
    #pragma unroll
    for (int h2 = 0; h2 < 2; ++h2) {
        __syncthreads();               // h2=0: A-reads done; h2=1: prev Cs reads done
        const int fl[4] = {flg[h2].x, flg[h2].y, flg[h2].z, flg[h2].w};
        #pragma unroll
        for (int j = 0; j < 4; ++j) {
            const float msk = (fl[j] == FLAG_MAGIC) ? 1.f : 0.f;
            float* crow = Cs + (hi * 4 + j) * CS_STRIDE + wcol + rl;
            #pragma unroll
            for (int n = 0; n < 4; ++n)
                crow[n * 16] = fmaf(msk, acc[h2][n][j], bov[n]);
        }
        __syncthreads();
        #pragma unroll
        for (int i = 0; i < 4; ++i) {
            const int rloc = wave * 4 + i;
            const f32x4 v = *(const f32x4*)(Cs + rloc * CS_STRIDE + lane * 4);
            const int r = row0 + h2 * 16 + rloc;
            if (r < NN)
                *(f32x4*)(out + (size_t)r * HID + lane * 4) = v;
        }
    }
}

// ---------------- launch ----------------

extern "C" void kernel_launch(void* const* d_in, const int* in_sizes, int n_in,
                              void* d_out, int out_size, void* d_ws, size_t ws_size,
                              hipStream_t stream) {
    const float* x   = (const float*)d_in[0];
    const int*   ei  = (const int*)d_in[1];
    const float* Wv  = (const float*)d_in[5];
    const float* Wo  = (const float*)d_in[7];
    const float* bo  = (const float*)d_in[8];
    float* out = (float*)d_out;

    unsigned short* wsB = (unsigned short*)d_ws;            // 128 KiB fragment image
    int* flags = (int*)((char*)d_ws + 4 * 32768);

    prep_k<<<NBLK_FLAG + HID, 256, 0, stream>>>(ei, flags, Wv, Wo, wsB);

    dim3 grid((NN + 31) / 32);
    out_gemm_k<<<grid, 256, 0, stream>>>(x, wsB, bo, flags, out);
}

// Round 11
// 33.181 us; speedup vs baseline: 1.7836x; 1.0040x over previous
//
#include <hip/hip_runtime.h>
#include <hip/hip_bf16.h>

#define NN 50000
#define NE 320000
#define HID 256
#define NBLK_FLAG 1250            // ceil(NE/256)
#define FLAG_MAGIC 0x7F3A9C51

typedef __attribute__((ext_vector_type(8))) short bf16x8;   // 8 bf16 = 4 VGPR
typedef __attribute__((ext_vector_type(4))) float f32x4;

static __device__ __forceinline__ short f2bf(float f) {
    union { __hip_bfloat16 h; short s; } u;
    u.h = __float2bfloat16(f);     // RNE; pairs pack to v_cvt_pk_bf16_f32
    return u.s;
}

// ---------------- prep: flags scatter + W2=Wv@Wo (bf16 fragment image) ----------------
// wsB layout = per-wave MFMA B fragments, coalesced:
//   byte off = kt*32768 + c16*2048 + kk*1024 + h*256 + rl*16 + e*2
// where k = kt*64 + kk*32 + h*8 + e, col = c16*16 + rl.
// Flags: idempotent FLAG_MAGIC scatter (inputs fixed); 0xAA poison never matches.
__global__ void prep_k(const int* __restrict__ ei, int* __restrict__ flags,
                       const float* __restrict__ Wv, const float* __restrict__ Wo,
                       unsigned short* __restrict__ wsB) {
    const int b = blockIdx.x;
    if (b < NBLK_FLAG) {
        __shared__ int nz;
        if (threadIdx.x == 0) nz = 0;
        __syncthreads();
        unsigned hv = ((const unsigned*)ei)[2 * threadIdx.x + 1];
        if (hv != 0u) nz = 1;              // benign same-value race
        __syncthreads();
        const int is64 = (nz == 0);        // int64 => high dwords all zero
        const int e = b * 256 + threadIdx.x;
        if (e < NE) {
            int t = is64 ? ei[2 * (NE + e)] : ei[NE + e];
            if (t >= 0 && t < NN) flags[t] = FLAG_MAGIC;   // benign same-value race
        }
    } else {
        const int i = b - NBLK_FLAG;       // W2 row == GEMM k, 0..255 (one row per block)
        const int j = threadIdx.x;         // col
        const float* wv = Wv + i * HID;    // wave-uniform scalar loads
        float s0 = 0.f, s1 = 0.f, s2 = 0.f, s3 = 0.f;
        #pragma unroll 8
        for (int k = 0; k < HID; k += 4) {
            s0 = fmaf(wv[k + 0], Wo[(k + 0) * HID + j], s0);
            s1 = fmaf(wv[k + 1], Wo[(k + 1) * HID + j], s1);
            s2 = fmaf(wv[k + 2], Wo[(k + 2) * HID + j], s2);
            s3 = fmaf(wv[k + 3], Wo[(k + 3) * HID + j], s3);
        }
        const float acc = (s0 + s1) + (s2 + s3);
        const int kt = i >> 6, kp = i & 63;
        const int kk = kp >> 5, h = (kp >> 3) & 3, e = kp & 7;
        wsB[(kt * 32768 + (j >> 4) * 2048 + kk * 1024 + h * 256 + (j & 15) * 16 + e * 2) >> 1]
            = (unsigned short)f2bf(acc);
    }
}

// ---------------- out = mask ? x @ W2 + bo : bo  (bf16 MFMA, VGPR-diet, 5 blk/CU) ----------------
// 256 threads (4 waves), tile 32 rows x 256 cols, grid 1563. Live-range separated:
// staging phase peaks ~50 VGPR (av8 + addr), compute phase ~90 (bfrag 32 + acc 32),
// so launch_bounds(256,5) fits without spill -> 20 waves/CU. B kt0 issued only
// after av dies into LDS. Flags loaded late. LDS-transpose full-row stores.

#define CS_STRIDE 260             // f32 per staged row (+4 pad)

__global__ __launch_bounds__(256, 5) void out_gemm_k(
    const float* __restrict__ x, const unsigned short* __restrict__ wsB,
    const float* __restrict__ bo, const int* __restrict__ flags,
    float* __restrict__ out)
{
    __shared__ char lds[16640];   // phase 1: A tiles 4x4KB; phase 2: 16 x 260 f32 C-stage
    float* Cs = (float*)lds;

    const int tid  = threadIdx.x;
    const int wave = tid >> 6;
    const int lane = tid & 63;
    const int rl   = lane & 15;
    const int hi   = lane >> 4;
    const int row0 = blockIdx.x * 32;
    const int wcol = wave * 64;

    // A staging map: thread -> (row ar = tid>>3, k-octet aq = tid&7)
    const int ar = tid >> 3;          // 0..31
    const int aq = tid & 7;           // 0..7  (8 k-floats each)
    int grow = row0 + ar; if (grow >= NN) grow = NN - 1;   // clamp tail (store masks)
    const float* asrc = x + (size_t)grow * HID + aq * 8;
    const int swr = (aq ^ (ar & 7)) << 4;                  // swizzled slot byte offset

    // ---- issue ALL A loads upfront (8 dwordx4/thread = 32KB tile in flight) ----
    {
        f32x4 av[8];
        #pragma unroll
        for (int kt = 0; kt < 4; ++kt) {
            av[2 * kt]     = *(const f32x4*)(asrc + kt * 64);
            av[2 * kt + 1] = *(const f32x4*)(asrc + kt * 64 + 4);
        }
        // convert + write 4 LDS A-buffers (av dies here, before B goes live)
        #pragma unroll
        for (int kt = 0; kt < 4; ++kt) {
            const f32x4 v0 = av[2 * kt], v1 = av[2 * kt + 1];
            bf16x8 w;
            w[0] = f2bf(v0[0]); w[1] = f2bf(v0[1]); w[2] = f2bf(v0[2]); w[3] = f2bf(v0[3]);
            w[4] = f2bf(v1[0]); w[5] = f2bf(v1[1]); w[6] = f2bf(v1[2]); w[7] = f2bf(v1[3]);
            *(bf16x8*)(lds + kt * 4096 + ar * 128 + swr) = w;
        }
    }

    // ---- B kt0 issue (after av dead) + bias ----
    const char* gB = (const char*)wsB + wave * 8192 + lane * 16;
    bf16x8 bfrag[4][2];
    #pragma unroll
    for (int n = 0; n < 4; ++n)
        #pragma unroll
        for (int kk = 0; kk < 2; ++kk)
            bfrag[n][kk] = *(const bf16x8*)(gB + n * 2048 + kk * 1024);
    float bov[4];
    #pragma unroll
    for (int n = 0; n < 4; ++n) bov[n] = bo[wcol + n * 16 + rl];

    __syncthreads();

    f32x4 acc[2][4];
    #pragma unroll
    for (int m = 0; m < 2; ++m)
        #pragma unroll
        for (int n = 0; n < 4; ++n)
            acc[m][n] = (f32x4){0.f, 0.f, 0.f, 0.f};

    int4 flg[2];

    // ---- MFMA loop, single-buffered B (load kt+1 after kt's last use) ----
    #pragma unroll
    for (int kt = 0; kt < 4; ++kt) {
        #pragma unroll
        for (int kk = 0; kk < 2; ++kk) {
            bf16x8 af[2];
            #pragma unroll
            for (int m = 0; m < 2; ++m)
                af[m] = *(const bf16x8*)(lds + kt * 4096 + (m * 16 + rl) * 128
                                         + ((((kk << 2) + hi) ^ (rl & 7)) << 4));
            #pragma unroll
            for (int m = 0; m < 2; ++m)
                #pragma unroll
                for (int n = 0; n < 4; ++n)
                    acc[m][n] = __builtin_amdgcn_mfma_f32_16x16x32_bf16(af[m], bfrag[n][kk], acc[m][n], 0, 0, 0);
        }
        if (kt < 3) {
            #pragma unroll
            for (int n = 0; n < 4; ++n)
                #pragma unroll
                for (int kk = 0; kk < 2; ++kk)
                    bfrag[n][kk] = *(const bf16x8*)(gB + (kt + 1) * 32768 + n * 2048 + kk * 1024);
        } else {
            #pragma unroll
            for (int m = 0; m < 2; ++m)
                flg[m] = *(const int4*)(flags + row0 + m * 16 + hi * 4);  // late; tail over-read in-ws
        }
    }

    // ---- epilogue: stage masked+biased acc through LDS; full-row dwordx4 stores ----
    #pragma unroll
    for (int h2 = 0; h2 < 2; ++h2) {
        __syncthreads();               // h2=0: A-reads done; h2=1: prev Cs reads done
        const int fl[4] = {flg[h2].x, flg[h2].y, flg[h2].z, flg[h2].w};
        #pragma unroll
        for (int j = 0; j < 4; ++j) {
            const float msk = (fl[j] == FLAG_MAGIC) ? 1.f : 0.f;
            float* crow = Cs + (hi * 4 + j) * CS_STRIDE + wcol + rl;
            #pragma unroll
            for (int n = 0; n < 4; ++n)
                crow[n * 16] = fmaf(msk, acc[h2][n][j], bov[n]);
        }
        __syncthreads();
        #pragma unroll
        for (int i = 0; i < 4; ++i) {
            const int rloc = wave * 4 + i;
            const f32x4 v = *(const f32x4*)(Cs + rloc * CS_STRIDE + lane * 4);
            const int r = row0 + h2 * 16 + rloc;
            if (r < NN)
                *(f32x4*)(out + (size_t)r * HID + lane * 4) = v;
        }
    }
}

// ---------------- launch ----------------

extern "C" void kernel_launch(void* const* d_in, const int* in_sizes, int n_in,
                              void* d_out, int out_size, void* d_ws, size_t ws_size,
                              hipStream_t stream) {
    const float* x   = (const float*)d_in[0];
    const int*   ei  = (const int*)d_in[1];
    const float* Wv  = (const float*)d_in[5];
    const float* Wo  = (const float*)d_in[7];
    const float* bo  = (const float*)d_in[8];
    float* out = (float*)d_out;

    unsigned short* wsB = (unsigned short*)d_ws;            // 128 KiB fragment image
    int* flags = (int*)((char*)d_ws + 4 * 32768);

    prep_k<<<NBLK_FLAG + HID, 256, 0, stream>>>(ei, flags, Wv, Wo, wsB);

    dim3 grid((NN + 31) / 32);
    out_gemm_k<<<grid, 256, 0, stream>>>(x, wsB, bo, flags, out);
}